// Round 4
// baseline (5839.420 us; speedup 1.0000x reference)
//
#include <hip/hip_runtime.h>
#include <math.h>

#define EPS 1e-5f

// ---------------- float offsets in ws (total 53,215,376 floats = 213 MB) ----------------
#define OFF_A  0u          // conv1 out [1024][8][28][11][11] = 27,754,496 (dead after conv2)
#define OFF_X0 0u          // tokens x  [1024][81][64] = 5,308,416 (written after A dead)
#define OFF_H  5308416u    // h / h2    [1024][81][64]
#define OFF_Q  10616832u   // Q, later Z [1024][4][81][16] / [1024][81][64]
#define OFF_K  15925248u   // K
#define OFF_V  21233664u   // V
#define OFF_YC 26542080u   // Yc        [1024][81][64]
#define OFF_Y  31850496u   // y         [1024][81][64]
#define OFF_F1 37158912u   // f1        [1024][81][128] = 10,616,832
#define OFF_B  47775744u   // conv2 out [1024][64][81] = 5,308,416
#define OFF_P  53084160u   // partials  131,072
#define OFF_ST 53215232u   // scale1[8] shift1[8] scale2[64] shift2[64]

// ---------------- kd1: conv3d + bias -> A ----------------
__global__ __launch_bounds__(256) void kd1_conv1(const float* X, const float* c3w,
                                                 const float* c3b, float* ws) {
  int idx = blockIdx.x * 256 + threadIdx.x;
  if (idx >= 27754496) return;
  int pos = idx;
  int w = pos % 11; pos /= 11;
  int h = pos % 11; pos /= 11;
  int dd = pos % 28; pos /= 28;
  int o1 = pos % 8;
  int b = pos / 8;
  const float* Xb = X + (size_t)b * 5070;
  float a = c3b[o1];
#pragma unroll
  for (int kd = 0; kd < 3; ++kd)
#pragma unroll
    for (int kh = 0; kh < 3; ++kh)
#pragma unroll
      for (int kw = 0; kw < 3; ++kw)
        a = fmaf(Xb[(dd+kd)*169 + (h+kh)*13 + (w+kw)],
                 c3w[o1*27 + kd*9 + kh*3 + kw], a);
  ws[OFF_A + idx] = a;
}

// ---------------- kd2: BN1 partial sums per (b, o1) ----------------
__global__ __launch_bounds__(256) void kd2_bn1part(const float* ws_in, float* ws) {
  __shared__ float sS[256], sQ[256];
  int blk = blockIdx.x;               // b*8 + o1
  int tid = threadIdx.x;
  const float* Ab = ws_in + OFF_A + (size_t)blk * 3388;
  float S = 0.f, Q = 0.f;
  for (int i = tid; i < 3388; i += 256) {
    float v = Ab[i];
    S += v; Q += v * v;
  }
  sS[tid] = S; sQ[tid] = Q;
  __syncthreads();
  for (int st = 128; st > 0; st >>= 1) {
    if (tid < st) { sS[tid] += sS[tid+st]; sQ[tid] += sQ[tid+st]; }
    __syncthreads();
  }
  if (tid == 0) {
    ws[OFF_P + blk*2]     = sS[0];
    ws[OFF_P + blk*2 + 1] = sQ[0];
  }
}

// ---------------- kd3: BN1 finalize (1 block, 64 threads) ----------------
__global__ void kd3_bn1fin(float* ws, const float* bn3g, const float* bn3b) {
  int t = threadIdx.x;
  if (t < 8) {
    float S = 0.f, Q = 0.f;
    for (int j = t; j < 8192; j += 8) {
      S += ws[OFF_P + j*2];
      Q += ws[OFF_P + j*2 + 1];
    }
    float n = 3469312.f;
    float mean = S / n;
    float var = Q / n - mean * mean;
    float sc = bn3g[t] * rsqrtf(var + EPS);
    ws[OFF_ST + t]     = sc;
    ws[OFF_ST + 8 + t] = bn3b[t] - mean * sc;
  }
}

// ---------------- kd4: apply BN1 + relu in place on A ----------------
__global__ __launch_bounds__(256) void kd4_bn1apply(float* ws) {
  int idx = blockIdx.x * 256 + threadIdx.x;
  if (idx >= 27754496) return;
  int ch = (idx / 3388) % 8;
  float v = ws[OFF_ST + ch] * ws[OFF_A + idx] + ws[OFF_ST + 8 + ch];
  ws[OFF_A + idx] = fmaxf(v, 0.f);
}

// ---------------- kd5: conv2 + bias -> B [b][oc][81] ----------------
__global__ __launch_bounds__(256) void kd5_conv2(const float* ws_in, const float* c2w,
                                                 const float* c2b, float* ws) {
  int idx = blockIdx.x * 256 + threadIdx.x;
  if (idx >= 5308416) return;
  int pos = idx;
  int x = pos % 9; pos /= 9;
  int y = pos % 9; pos /= 9;
  int oc = pos % 64;
  int b = pos / 64;
  const float* Ab = ws_in + OFF_A + (size_t)b * 27104;  // [224][11][11]
  const float* Wc = c2w + (size_t)oc * 2016;            // [224][3][3]
  float a = c2b[oc];
  for (int ci = 0; ci < 224; ++ci) {
    const float* Ar = Ab + ci * 121;
    const float* Wr = Wc + ci * 9;
#pragma unroll
    for (int ki = 0; ki < 3; ++ki)
#pragma unroll
      for (int kj = 0; kj < 3; ++kj)
        a = fmaf(Ar[(y+ki)*11 + (x+kj)], Wr[ki*3 + kj], a);
  }
  ws[OFF_B + idx] = a;  // idx = b*5184 + oc*81 + y*9 + x
}

// ---------------- kd6: BN2 partials per b (64 threads) ----------------
__global__ void kd6_bn2part(const float* ws_in, float* ws) {
  int b = blockIdx.x, t = threadIdx.x;  // t = channel
  const float* Bb = ws_in + OFF_B + (size_t)b * 5184 + t * 81;
  float S = 0.f, Q = 0.f;
  for (int s = 0; s < 81; ++s) {
    float v = Bb[s];
    S += v; Q += v * v;
  }
  ws[OFF_P + b*128 + t]      = S;
  ws[OFF_P + b*128 + 64 + t] = Q;
}

// ---------------- kd7: BN2 finalize (1 block, 64 threads) ----------------
__global__ void kd7_bn2fin(float* ws, const float* bn2g, const float* bn2b) {
  int t = threadIdx.x;
  float S = 0.f, Q = 0.f;
  for (int b = 0; b < 1024; ++b) {
    S += ws[OFF_P + b*128 + t];
    Q += ws[OFF_P + b*128 + 64 + t];
  }
  float n = 82944.f;
  float mean = S / n;
  float var = Q / n - mean * mean;
  float sc = bn2g[t] * rsqrtf(var + EPS);
  ws[OFF_ST + 16 + t] = sc;
  ws[OFF_ST + 80 + t] = bn2b[t] - mean * sc;
}

// ---------------- kd8: BN2 apply + relu + transpose -> X0 [b][s][64] ----------------
__global__ __launch_bounds__(256) void kd8_tokens(float* ws) {
  int idx = blockIdx.x * 256 + threadIdx.x;
  if (idx >= 5308416) return;
  int o = idx % 64;
  int s = (idx / 64) % 81;
  int b = idx / 5184;
  float v = ws[OFF_ST + 16 + o] * ws[OFF_B + (size_t)b*5184 + o*81 + s] + ws[OFF_ST + 80 + o];
  ws[OFF_X0 + idx] = fmaxf(v, 0.f);
}

// ---------------- kd9: LayerNorm (generic) src row -> dst row ----------------
__global__ __launch_bounds__(256) void kd9_ln(const float* ws_in, float* ws,
                                              unsigned int src_off, unsigned int dst_off,
                                              const float* g, const float* bb, int l) {
  int idx = blockIdx.x * 256 + threadIdx.x;
  if (idx >= 82944) return;   // (b, s)
  const float* xr = ws_in + src_off + (size_t)idx * 64;
  float* hr = ws + dst_off + (size_t)idx * 64;
  float sv = 0.f;
  for (int d = 0; d < 64; ++d) sv += xr[d];
  float mean = sv * (1.f / 64.f);
  float sq = 0.f;
  for (int d = 0; d < 64; ++d) { float dv = xr[d] - mean; sq += dv * dv; }
  float rstd = rsqrtf(sq * (1.f / 64.f) + EPS);
  for (int d = 0; d < 64; ++d)
    hr[d] = (xr[d] - mean) * rstd * g[l*64 + d] + bb[l*64 + d];
}

// ---------------- kd10: Q/K/V projections ----------------
__global__ __launch_bounds__(256) void kd10_qkv(const float* ws_in, float* ws,
                                                const float* wq, const float* wk,
                                                const float* wv, int l) {
  int idx = blockIdx.x * 256 + threadIdx.x;
  if (idx >= 15925248) return;
  int m = idx / 5308416;
  int r = idx - m * 5308416;
  int k = r % 16;
  int s = (r / 16) % 81;
  int h = (r / 1296) % 4;
  int b = r / 5184;
  const float* src = (m == 0) ? wq : (m == 1) ? wk : wv;
  const float* Hr = ws_in + OFF_H + ((size_t)b * 81 + s) * 64;
  float a = 0.f;
  for (int d = 0; d < 64; ++d)
    a = fmaf(Hr[d], src[((l*4 + h)*64 + d)*16 + k], a);
  unsigned int dst = (m == 0) ? OFF_Q : (m == 1) ? OFF_K : OFF_V;
  ws[dst + (size_t)b*5184 + (h*81 + s)*16 + k] = a;
}

// ---------------- kd11: xPos rotary on Q (m=0) and K (m=1), in place ----------------
__global__ __launch_bounds__(256) void kd11_rot(float* ws) {
  int idx = blockIdx.x * 256 + threadIdx.x;
  if (idx >= 5308416) return;
  int m = idx / 2654208;
  int r = idx - m * 2654208;
  int p = r % 8;
  int s = (r / 8) % 81;
  int h = (r / 648) % 4;
  int b = r / 2592;
  float scale = (2.f * p + 6.4f) / 22.4f;
  float xs = powf(scale, (float)s / 512.f);
  float invf = powf(10000.f, -(float)p / 8.f);
  float ang = (float)s * invf;
  float c = cosf(ang), sn = sinf(ang);
  float cu, su;
  if (m == 0) { cu = c * xs; su = sn * xs; }
  else        { cu = c / xs; su = sn / xs; }
  float* ptr = ws + ((m == 0) ? OFF_Q : OFF_K) + (size_t)b*5184 + (h*81 + s)*16 + 2*p;
  float a = ptr[0], bb = ptr[1];
  ptr[0] = a * cu - bb * su;
  ptr[1] = bb * cu + a * su;
}

// ---------------- kd12: retention attention + per-head groupnorm -> Yc ----------------
__global__ __launch_bounds__(256) void kd12_attn(const float* ws_in, float* ws,
                                                 const float* gng, const float* gnb, int l) {
  int idx = blockIdx.x * 256 + threadIdx.x;
  if (idx >= 331776) return;
  int s = idx % 81;
  int h = (idx / 81) % 4;
  int b = idx / 324;
  float g = 1.f - expf(-3.4657359f + (float)h * (-0.92419624f));
  float lg = log2f(g);
  const float* Qr = ws_in + OFF_Q + (size_t)b*5184 + (h*81 + s)*16;
  float q[16];
#pragma unroll
  for (int k = 0; k < 16; ++k) q[k] = Qr[k];
  float yh[16];
#pragma unroll
  for (int v = 0; v < 16; ++v) yh[v] = 0.f;
  const float* Kb = ws_in + OFF_K + (size_t)b*5184 + h*81*16;
  const float* Vb = ws_in + OFF_V + (size_t)b*5184 + h*81*16;
  for (int t = 0; t <= s; ++t) {
    const float* Kr = Kb + t*16;
    float a = 0.f;
#pragma unroll
    for (int k = 0; k < 16; ++k) a = fmaf(q[k], Kr[k], a);
    a *= exp2f((float)(s - t) * lg);
    const float* Vr = Vb + t*16;
#pragma unroll
    for (int v = 0; v < 16; ++v) yh[v] = fmaf(a, Vr[v], yh[v]);
  }
  float sv = 0.f;
#pragma unroll
  for (int v = 0; v < 16; ++v) sv += yh[v];
  float mean = sv * (1.f / 16.f);
  float sq = 0.f;
#pragma unroll
  for (int v = 0; v < 16; ++v) { float dv = yh[v] - mean; sq += dv * dv; }
  float rstd = rsqrtf(sq * (1.f / 16.f) + EPS);
  float* Yr = ws + OFF_YC + ((size_t)b*81 + s)*64 + h*16;
#pragma unroll
  for (int v = 0; v < 16; ++v) {
    int col = h*16 + v;
    Yr[v] = (yh[v] - mean) * rstd * gng[l*64 + col] + gnb[l*64 + col];
  }
}

// ---------------- kd13: G = H@wg; Z = silu(G) * Yc  (Z in Q buffer) ----------------
__global__ __launch_bounds__(256) void kd13_gate(const float* ws_in, float* ws,
                                                 const float* wg, int l) {
  int idx = blockIdx.x * 256 + threadIdx.x;
  if (idx >= 5308416) return;
  int c = idx % 64;
  int bs = idx / 64;
  const float* Hr = ws_in + OFF_H + (size_t)bs * 64;
  float G = 0.f;
  for (int d = 0; d < 64; ++d)
    G = fmaf(Hr[d], wg[(l*64 + d)*64 + c], G);
  float sig = 1.f / (1.f + expf(-G));
  ws[OFF_Q + idx] = G * sig * ws_in[OFF_YC + idx];
}

// ---------------- kd14: Y = Z@wo + X0 ----------------
__global__ __launch_bounds__(256) void kd14_wo(const float* ws_in, float* ws,
                                               const float* wo, int l) {
  int idx = blockIdx.x * 256 + threadIdx.x;
  if (idx >= 5308416) return;
  int c = idx % 64;
  int bs = idx / 64;
  const float* Zr = ws_in + OFF_Q + (size_t)bs * 64;
  float a = 0.f;
  for (int d = 0; d < 64; ++d)
    a = fmaf(Zr[d], wo[(l*64 + d)*64 + c], a);
  ws[OFF_Y + idx] = a + ws_in[OFF_X0 + idx];
}

// ---------------- kd16: F1 = gelu(H2@fw1 + fb1) ----------------
__global__ __launch_bounds__(256) void kd16_ffn1(const float* ws_in, float* ws,
                                                 const float* fw1, const float* fb1, int l) {
  int idx = blockIdx.x * 256 + threadIdx.x;
  if (idx >= 10616832) return;
  int f = idx % 128;
  int bs = idx / 128;
  const float* Hr = ws_in + OFF_H + (size_t)bs * 64;
  float p = fb1[l*128 + f];
  for (int d = 0; d < 64; ++d)
    p = fmaf(Hr[d], fw1[(l*64 + d)*128 + f], p);
  ws[OFF_F1 + idx] = 0.5f * p * (1.f + erff(p * 0.70710678118f));
}

// ---------------- kd17: X0 = F1@fw2 + fb2 + Y ----------------
__global__ __launch_bounds__(256) void kd17_ffn2(const float* ws_in, float* ws,
                                                 const float* fw2, const float* fb2, int l) {
  int idx = blockIdx.x * 256 + threadIdx.x;
  if (idx >= 5308416) return;
  int c = idx % 64;
  int bs = idx / 64;
  const float* Fr = ws_in + OFF_F1 + (size_t)bs * 128;
  float a = fb2[l*64 + c];
  for (int f = 0; f < 128; ++f)
    a = fmaf(Fr[f], fw2[(l*128 + f)*64 + c], a);
  ws[OFF_X0 + idx] = a + ws_in[OFF_Y + idx];
}

// ---------------- kd18: classifier ----------------
__global__ __launch_bounds__(256) void kd18_cls(const float* ws_in, const float* nn1w,
                                                const float* nn1b, float* out) {
  int idx = blockIdx.x * 256 + threadIdx.x;
  if (idx >= 16384) return;
  int c = idx % 16;
  int b = idx / 16;
  const float* Xr = ws_in + OFF_X0 + (size_t)b * 5184;
  float a = nn1b[c];
  for (int i = 0; i < 5184; ++i)
    a = fmaf(Xr[i], nn1w[i*16 + c], a);
  out[idx] = a;
}

// ---------------- launch ----------------
extern "C" void kernel_launch(void* const* d_in, const int* in_sizes, int n_in,
                              void* d_out, int out_size, void* d_ws, size_t ws_size,
                              hipStream_t stream) {
  const float* X    = (const float*)d_in[0];
  const float* c3w  = (const float*)d_in[1];
  const float* c3b  = (const float*)d_in[2];
  const float* bn3g = (const float*)d_in[3];
  const float* bn3b = (const float*)d_in[4];
  const float* c2w  = (const float*)d_in[5];
  const float* c2b  = (const float*)d_in[6];
  const float* bn2g = (const float*)d_in[7];
  const float* bn2b = (const float*)d_in[8];
  const float* wq   = (const float*)d_in[9];
  const float* wk   = (const float*)d_in[10];
  const float* wv   = (const float*)d_in[11];
  const float* wg   = (const float*)d_in[12];
  const float* wo   = (const float*)d_in[13];
  const float* gng  = (const float*)d_in[14];
  const float* gnb  = (const float*)d_in[15];
  const float* ln1g = (const float*)d_in[16];
  const float* ln1b = (const float*)d_in[17];
  const float* ln2g = (const float*)d_in[18];
  const float* ln2b = (const float*)d_in[19];
  const float* fw1  = (const float*)d_in[20];
  const float* fb1  = (const float*)d_in[21];
  const float* fw2  = (const float*)d_in[22];
  const float* fb2  = (const float*)d_in[23];
  const float* nn1w = (const float*)d_in[24];
  const float* nn1b = (const float*)d_in[25];
  float* ws = (float*)d_ws;
  float* out = (float*)d_out;

  // conv stage
  kd1_conv1<<<108416, 256, 0, stream>>>(X, c3w, c3b, ws);
  kd2_bn1part<<<8192, 256, 0, stream>>>(ws, ws);
  kd3_bn1fin<<<1, 64, 0, stream>>>(ws, bn3g, bn3b);
  kd4_bn1apply<<<108416, 256, 0, stream>>>(ws);
  kd5_conv2<<<20736, 256, 0, stream>>>(ws, c2w, c2b, ws);
  kd6_bn2part<<<1024, 64, 0, stream>>>(ws, ws);
  kd7_bn2fin<<<1, 64, 0, stream>>>(ws, bn2g, bn2b);
  kd8_tokens<<<20736, 256, 0, stream>>>(ws);

  // transformer layers
  for (int l = 0; l < 2; ++l) {
    kd9_ln<<<324, 256, 0, stream>>>(ws, ws, OFF_X0, OFF_H, ln1g, ln1b, l);
    kd10_qkv<<<62208, 256, 0, stream>>>(ws, ws, wq, wk, wv, l);
    kd11_rot<<<20736, 256, 0, stream>>>(ws);
    kd12_attn<<<1296, 256, 0, stream>>>(ws, ws, gng, gnb, l);
    kd13_gate<<<20736, 256, 0, stream>>>(ws, ws, wg, l);
    kd14_wo<<<20736, 256, 0, stream>>>(ws, ws, wo, l);
    kd9_ln<<<324, 256, 0, stream>>>(ws, ws, OFF_Y, OFF_H, ln2g, ln2b, l);
    kd16_ffn1<<<41472, 256, 0, stream>>>(ws, ws, fw1, fb1, l);
    kd17_ffn2<<<20736, 256, 0, stream>>>(ws, ws, fw2, fb2, l);
  }

  kd18_cls<<<64, 256, 0, stream>>>(ws, nn1w, nn1b, out);
}

// Round 5
// 3299.640 us; speedup vs baseline: 1.7697x; 1.7697x over previous
//
#include <hip/hip_runtime.h>
#include <math.h>

#define EPS 1e-5f

// ---------------- float offsets in ws (total 53,215,376 floats = 213 MB) ----------------
#define OFF_A  0u          // conv1 out [1024][8][28][11][11] = 27,754,496 (dead after conv2)
#define OFF_X0 0u          // tokens x  [1024][81][64] = 5,308,416 (written after A dead)
#define OFF_H  5308416u    // h / h2    [1024][81][64]
#define OFF_Q  10616832u   // Q, later Z [1024][4][81][16] / [1024][81][64]
#define OFF_K  15925248u   // K
#define OFF_V  21233664u   // V
#define OFF_YC 26542080u   // Yc        [1024][81][64]
#define OFF_Y  31850496u   // y         [1024][81][64]
#define OFF_F1 37158912u   // f1        [1024][81][128] = 10,616,832
#define OFF_B  47775744u   // conv2 out [1024][64][81] = 5,308,416
#define OFF_P  53084160u   // partials  131,072
#define OFF_ST 53215232u   // scale1[8] shift1[8] scale2[64] shift2[64]

// ---------------- kd1: conv3d + bias -> A ----------------
__global__ __launch_bounds__(256) void kd1_conv1(const float* X, const float* c3w,
                                                 const float* c3b, float* ws) {
  int idx = blockIdx.x * 256 + threadIdx.x;
  if (idx >= 27754496) return;
  int pos = idx;
  int w = pos % 11; pos /= 11;
  int h = pos % 11; pos /= 11;
  int dd = pos % 28; pos /= 28;
  int o1 = pos % 8;
  int b = pos / 8;
  const float* Xb = X + (size_t)b * 5070;
  float a = c3b[o1];
#pragma unroll
  for (int kd = 0; kd < 3; ++kd)
#pragma unroll
    for (int kh = 0; kh < 3; ++kh)
#pragma unroll
      for (int kw = 0; kw < 3; ++kw)
        a = fmaf(Xb[(dd+kd)*169 + (h+kh)*13 + (w+kw)],
                 c3w[o1*27 + kd*9 + kh*3 + kw], a);
  ws[OFF_A + idx] = a;
}

// ---------------- kd2: BN1 partial sums per (b, o1) ----------------
__global__ __launch_bounds__(256) void kd2_bn1part(const float* ws_in, float* ws) {
  __shared__ float sS[256], sQ[256];
  int blk = blockIdx.x;               // b*8 + o1
  int tid = threadIdx.x;
  const float* Ab = ws_in + OFF_A + (size_t)blk * 3388;
  float S = 0.f, Q = 0.f;
  for (int i = tid; i < 3388; i += 256) {
    float v = Ab[i];
    S += v; Q += v * v;
  }
  sS[tid] = S; sQ[tid] = Q;
  __syncthreads();
  for (int st = 128; st > 0; st >>= 1) {
    if (tid < st) { sS[tid] += sS[tid+st]; sQ[tid] += sQ[tid+st]; }
    __syncthreads();
  }
  if (tid == 0) {
    ws[OFF_P + blk*2]     = sS[0];
    ws[OFF_P + blk*2 + 1] = sQ[0];
  }
}

// ---------------- kd3: BN1 finalize (1 block, 64 threads) ----------------
__global__ void kd3_bn1fin(float* ws, const float* bn3g, const float* bn3b) {
  int t = threadIdx.x;
  if (t < 8) {
    float S = 0.f, Q = 0.f;
    for (int j = t; j < 8192; j += 8) {
      S += ws[OFF_P + j*2];
      Q += ws[OFF_P + j*2 + 1];
    }
    float n = 3469312.f;
    float mean = S / n;
    float var = Q / n - mean * mean;
    float sc = bn3g[t] * rsqrtf(var + EPS);
    ws[OFF_ST + t]     = sc;
    ws[OFF_ST + 8 + t] = bn3b[t] - mean * sc;
  }
}

// ---------------- kd4: apply BN1 + relu in place on A ----------------
__global__ __launch_bounds__(256) void kd4_bn1apply(float* ws) {
  int idx = blockIdx.x * 256 + threadIdx.x;
  if (idx >= 27754496) return;
  int ch = (idx / 3388) % 8;
  float v = ws[OFF_ST + ch] * ws[OFF_A + idx] + ws[OFF_ST + 8 + ch];
  ws[OFF_A + idx] = fmaxf(v, 0.f);
}

// ---------------- kd5: conv2, per-batch LDS-tiled (64oc x 3 row-groups = 192 thr) ----------------
__global__ __launch_bounds__(192) void kd5_conv2(const float* ws_in, const float* c2w,
                                                 const float* c2b, float* ws) {
  __shared__ float wl[4752];    // [kk 9][ciL 8][oc pad 66]
  __shared__ float inl[1056];   // [ciL 8][11 rows x 12]
  int tid = threadIdx.x;
  int b = blockIdx.x;
  int o = tid / 3, q = tid - o*3;
  const float* Ab = ws_in + OFF_A + (size_t)b * 27104;   // [224][11][11]
  float acc[3][9];
#pragma unroll
  for (int ir = 0; ir < 3; ++ir)
#pragma unroll
    for (int x = 0; x < 9; ++x) acc[ir][x] = 0.f;

  for (int cc = 0; cc < 28; ++cc) {
    __syncthreads();   // previous iteration's LDS reads complete
    // stage weight chunk: 64 oc x 8 ci x 9 = 4608 elements
#pragma unroll
    for (int it = 0; it < 24; ++it) {
      int j = tid + 192*it;
      int og = j / 72, r = j - og*72;
      int ciL = r / 9, kk = r - ciL*9;
      wl[kk*528 + ciL*66 + og] = c2w[(og*224 + cc*8 + ciL)*9 + kk];
    }
    // stage input chunk: 8 x 121 = 968 elements (row stride padded to 12)
#pragma unroll
    for (int it = 0; it < 6; ++it) {
      int e = tid + 192*it;
      if (e < 968) {
        int ciL = e / 121, pos = e - ciL*121;
        int h = pos / 11, w = pos - h*11;
        inl[ciL*132 + h*12 + w] = Ab[(cc*8 + ciL)*121 + pos];
      }
    }
    __syncthreads();
    for (int ciL = 0; ciL < 8; ++ciL) {
      // load the 5 input rows this thread's 3 output rows need
      float rr[5][12];
#pragma unroll
      for (int r5 = 0; r5 < 5; ++r5) {
        const float4* rp = (const float4*)(inl + ciL*132 + (q*3 + r5)*12);
        float4 A4 = rp[0], B4 = rp[1], C4 = rp[2];
        rr[r5][0]=A4.x; rr[r5][1]=A4.y; rr[r5][2]=A4.z; rr[r5][3]=A4.w;
        rr[r5][4]=B4.x; rr[r5][5]=B4.y; rr[r5][6]=B4.z; rr[r5][7]=B4.w;
        rr[r5][8]=C4.x; rr[r5][9]=C4.y; rr[r5][10]=C4.z; rr[r5][11]=C4.w;
      }
#pragma unroll
      for (int ki = 0; ki < 3; ++ki) {
#pragma unroll
        for (int kj = 0; kj < 3; ++kj) {
          float wv = wl[(ki*3+kj)*528 + ciL*66 + o];
#pragma unroll
          for (int ir = 0; ir < 3; ++ir)
#pragma unroll
            for (int x = 0; x < 9; ++x)
              acc[ir][x] = fmaf(rr[ir+ki][x+kj], wv, acc[ir][x]);
        }
      }
    }
  }
  // bias + store  B[b][oc][y*9+x]
  float bias = c2b[o];
  float* b2 = ws + OFF_B + ((size_t)b*64 + o)*81;
#pragma unroll
  for (int ir = 0; ir < 3; ++ir)
#pragma unroll
    for (int x = 0; x < 9; ++x)
      b2[(q*3+ir)*9 + x] = acc[ir][x] + bias;
}

// ---------------- kd6: BN2 partials per b (64 threads) ----------------
__global__ void kd6_bn2part(const float* ws_in, float* ws) {
  int b = blockIdx.x, t = threadIdx.x;  // t = channel
  const float* Bb = ws_in + OFF_B + (size_t)b * 5184 + t * 81;
  float S = 0.f, Q = 0.f;
  for (int s = 0; s < 81; ++s) {
    float v = Bb[s];
    S += v; Q += v * v;
  }
  ws[OFF_P + b*128 + t]      = S;
  ws[OFF_P + b*128 + 64 + t] = Q;
}

// ---------------- kd7: BN2 finalize (1 block, 64 threads) ----------------
__global__ void kd7_bn2fin(float* ws, const float* bn2g, const float* bn2b) {
  int t = threadIdx.x;
  float S = 0.f, Q = 0.f;
  for (int b = 0; b < 1024; ++b) {
    S += ws[OFF_P + b*128 + t];
    Q += ws[OFF_P + b*128 + 64 + t];
  }
  float n = 82944.f;
  float mean = S / n;
  float var = Q / n - mean * mean;
  float sc = bn2g[t] * rsqrtf(var + EPS);
  ws[OFF_ST + 16 + t] = sc;
  ws[OFF_ST + 80 + t] = bn2b[t] - mean * sc;
}

// ---------------- kd8: BN2 apply + relu + transpose -> X0 [b][s][64] ----------------
__global__ __launch_bounds__(256) void kd8_tokens(float* ws) {
  int idx = blockIdx.x * 256 + threadIdx.x;
  if (idx >= 5308416) return;
  int o = idx % 64;
  int s = (idx / 64) % 81;
  int b = idx / 5184;
  float v = ws[OFF_ST + 16 + o] * ws[OFF_B + (size_t)b*5184 + o*81 + s] + ws[OFF_ST + 80 + o];
  ws[OFF_X0 + idx] = fmaxf(v, 0.f);
}

// ---------------- kd9: LayerNorm (generic) src row -> dst row ----------------
__global__ __launch_bounds__(256) void kd9_ln(const float* ws_in, float* ws,
                                              unsigned int src_off, unsigned int dst_off,
                                              const float* g, const float* bb, int l) {
  int idx = blockIdx.x * 256 + threadIdx.x;
  if (idx >= 82944) return;   // (b, s)
  const float* xr = ws_in + src_off + (size_t)idx * 64;
  float* hr = ws + dst_off + (size_t)idx * 64;
  float sv = 0.f;
  for (int d = 0; d < 64; ++d) sv += xr[d];
  float mean = sv * (1.f / 64.f);
  float sq = 0.f;
  for (int d = 0; d < 64; ++d) { float dv = xr[d] - mean; sq += dv * dv; }
  float rstd = rsqrtf(sq * (1.f / 64.f) + EPS);
  for (int d = 0; d < 64; ++d)
    hr[d] = (xr[d] - mean) * rstd * g[l*64 + d] + bb[l*64 + d];
}

// ---------------- kd10: Q/K/V projections ----------------
__global__ __launch_bounds__(256) void kd10_qkv(const float* ws_in, float* ws,
                                                const float* wq, const float* wk,
                                                const float* wv, int l) {
  int idx = blockIdx.x * 256 + threadIdx.x;
  if (idx >= 15925248) return;
  int m = idx / 5308416;
  int r = idx - m * 5308416;
  int k = r % 16;
  int s = (r / 16) % 81;
  int h = (r / 1296) % 4;
  int b = r / 5184;
  const float* src = (m == 0) ? wq : (m == 1) ? wk : wv;
  const float* Hr = ws_in + OFF_H + ((size_t)b * 81 + s) * 64;
  float a = 0.f;
  for (int d = 0; d < 64; ++d)
    a = fmaf(Hr[d], src[((l*4 + h)*64 + d)*16 + k], a);
  unsigned int dst = (m == 0) ? OFF_Q : (m == 1) ? OFF_K : OFF_V;
  ws[dst + (size_t)b*5184 + (h*81 + s)*16 + k] = a;
}

// ---------------- kd11: xPos rotary on Q (m=0) and K (m=1), in place ----------------
__global__ __launch_bounds__(256) void kd11_rot(float* ws) {
  int idx = blockIdx.x * 256 + threadIdx.x;
  if (idx >= 5308416) return;
  int m = idx / 2654208;
  int r = idx - m * 2654208;
  int p = r % 8;
  int s = (r / 8) % 81;
  int h = (r / 648) % 4;
  int b = r / 2592;
  float scale = (2.f * p + 6.4f) / 22.4f;
  float xs = powf(scale, (float)s / 512.f);
  float invf = powf(10000.f, -(float)p / 8.f);
  float ang = (float)s * invf;
  float c = cosf(ang), sn = sinf(ang);
  float cu, su;
  if (m == 0) { cu = c * xs; su = sn * xs; }
  else        { cu = c / xs; su = sn / xs; }
  float* ptr = ws + ((m == 0) ? OFF_Q : OFF_K) + (size_t)b*5184 + (h*81 + s)*16 + 2*p;
  float a = ptr[0], bb = ptr[1];
  ptr[0] = a * cu - bb * su;
  ptr[1] = bb * cu + a * su;
}

// ---------------- kd12: retention attention + per-head groupnorm -> Yc ----------------
__global__ __launch_bounds__(256) void kd12_attn(const float* ws_in, float* ws,
                                                 const float* gng, const float* gnb, int l) {
  int idx = blockIdx.x * 256 + threadIdx.x;
  if (idx >= 331776) return;
  int s = idx % 81;
  int h = (idx / 81) % 4;
  int b = idx / 324;
  float g = 1.f - expf(-3.4657359f + (float)h * (-0.92419624f));
  float lg = log2f(g);
  const float* Qr = ws_in + OFF_Q + (size_t)b*5184 + (h*81 + s)*16;
  float q[16];
#pragma unroll
  for (int k = 0; k < 16; ++k) q[k] = Qr[k];
  float yh[16];
#pragma unroll
  for (int v = 0; v < 16; ++v) yh[v] = 0.f;
  const float* Kb = ws_in + OFF_K + (size_t)b*5184 + h*81*16;
  const float* Vb = ws_in + OFF_V + (size_t)b*5184 + h*81*16;
  for (int t = 0; t <= s; ++t) {
    const float* Kr = Kb + t*16;
    float a = 0.f;
#pragma unroll
    for (int k = 0; k < 16; ++k) a = fmaf(q[k], Kr[k], a);
    a *= exp2f((float)(s - t) * lg);
    const float* Vr = Vb + t*16;
#pragma unroll
    for (int v = 0; v < 16; ++v) yh[v] = fmaf(a, Vr[v], yh[v]);
  }
  float sv = 0.f;
#pragma unroll
  for (int v = 0; v < 16; ++v) sv += yh[v];
  float mean = sv * (1.f / 16.f);
  float sq = 0.f;
#pragma unroll
  for (int v = 0; v < 16; ++v) { float dv = yh[v] - mean; sq += dv * dv; }
  float rstd = rsqrtf(sq * (1.f / 16.f) + EPS);
  float* Yr = ws + OFF_YC + ((size_t)b*81 + s)*64 + h*16;
#pragma unroll
  for (int v = 0; v < 16; ++v) {
    int col = h*16 + v;
    Yr[v] = (yh[v] - mean) * rstd * gng[l*64 + col] + gnb[l*64 + col];
  }
}

// ---------------- kd13: G = H@wg; Z = silu(G) * Yc  (Z in Q buffer) ----------------
__global__ __launch_bounds__(256) void kd13_gate(const float* ws_in, float* ws,
                                                 const float* wg, int l) {
  int idx = blockIdx.x * 256 + threadIdx.x;
  if (idx >= 5308416) return;
  int c = idx % 64;
  int bs = idx / 64;
  const float* Hr = ws_in + OFF_H + (size_t)bs * 64;
  float G = 0.f;
  for (int d = 0; d < 64; ++d)
    G = fmaf(Hr[d], wg[(l*64 + d)*64 + c], G);
  float sig = 1.f / (1.f + expf(-G));
  ws[OFF_Q + idx] = G * sig * ws_in[OFF_YC + idx];
}

// ---------------- kd14: Y = Z@wo + X0 ----------------
__global__ __launch_bounds__(256) void kd14_wo(const float* ws_in, float* ws,
                                               const float* wo, int l) {
  int idx = blockIdx.x * 256 + threadIdx.x;
  if (idx >= 5308416) return;
  int c = idx % 64;
  int bs = idx / 64;
  const float* Zr = ws_in + OFF_Q + (size_t)bs * 64;
  float a = 0.f;
  for (int d = 0; d < 64; ++d)
    a = fmaf(Zr[d], wo[(l*64 + d)*64 + c], a);
  ws[OFF_Y + idx] = a + ws_in[OFF_X0 + idx];
}

// ---------------- kd16: F1 = gelu(H2@fw1 + fb1) ----------------
__global__ __launch_bounds__(256) void kd16_ffn1(const float* ws_in, float* ws,
                                                 const float* fw1, const float* fb1, int l) {
  int idx = blockIdx.x * 256 + threadIdx.x;
  if (idx >= 10616832) return;
  int f = idx % 128;
  int bs = idx / 128;
  const float* Hr = ws_in + OFF_H + (size_t)bs * 64;
  float p = fb1[l*128 + f];
  for (int d = 0; d < 64; ++d)
    p = fmaf(Hr[d], fw1[(l*64 + d)*128 + f], p);
  ws[OFF_F1 + idx] = 0.5f * p * (1.f + erff(p * 0.70710678118f));
}

// ---------------- kd17: X0 = F1@fw2 + fb2 + Y ----------------
__global__ __launch_bounds__(256) void kd17_ffn2(const float* ws_in, float* ws,
                                                 const float* fw2, const float* fb2, int l) {
  int idx = blockIdx.x * 256 + threadIdx.x;
  if (idx >= 5308416) return;
  int c = idx % 64;
  int bs = idx / 64;
  const float* Fr = ws_in + OFF_F1 + (size_t)bs * 128;
  float a = fb2[l*64 + c];
  for (int f = 0; f < 128; ++f)
    a = fmaf(Fr[f], fw2[(l*128 + f)*64 + c], a);
  ws[OFF_X0 + idx] = a + ws_in[OFF_Y + idx];
}

// ---------------- kd18: classifier ----------------
__global__ __launch_bounds__(256) void kd18_cls(const float* ws_in, const float* nn1w,
                                                const float* nn1b, float* out) {
  int idx = blockIdx.x * 256 + threadIdx.x;
  if (idx >= 16384) return;
  int c = idx % 16;
  int b = idx / 16;
  const float* Xr = ws_in + OFF_X0 + (size_t)b * 5184;
  float a = nn1b[c];
  for (int i = 0; i < 5184; ++i)
    a = fmaf(Xr[i], nn1w[i*16 + c], a);
  out[idx] = a;
}

// ---------------- launch ----------------
extern "C" void kernel_launch(void* const* d_in, const int* in_sizes, int n_in,
                              void* d_out, int out_size, void* d_ws, size_t ws_size,
                              hipStream_t stream) {
  const float* X    = (const float*)d_in[0];
  const float* c3w  = (const float*)d_in[1];
  const float* c3b  = (const float*)d_in[2];
  const float* bn3g = (const float*)d_in[3];
  const float* bn3b = (const float*)d_in[4];
  const float* c2w  = (const float*)d_in[5];
  const float* c2b  = (const float*)d_in[6];
  const float* bn2g = (const float*)d_in[7];
  const float* bn2b = (const float*)d_in[8];
  const float* wq   = (const float*)d_in[9];
  const float* wk   = (const float*)d_in[10];
  const float* wv   = (const float*)d_in[11];
  const float* wg   = (const float*)d_in[12];
  const float* wo   = (const float*)d_in[13];
  const float* gng  = (const float*)d_in[14];
  const float* gnb  = (const float*)d_in[15];
  const float* ln1g = (const float*)d_in[16];
  const float* ln1b = (const float*)d_in[17];
  const float* ln2g = (const float*)d_in[18];
  const float* ln2b = (const float*)d_in[19];
  const float* fw1  = (const float*)d_in[20];
  const float* fb1  = (const float*)d_in[21];
  const float* fw2  = (const float*)d_in[22];
  const float* fb2  = (const float*)d_in[23];
  const float* nn1w = (const float*)d_in[24];
  const float* nn1b = (const float*)d_in[25];
  float* ws = (float*)d_ws;
  float* out = (float*)d_out;

  // conv stage
  kd1_conv1<<<108416, 256, 0, stream>>>(X, c3w, c3b, ws);
  kd2_bn1part<<<8192, 256, 0, stream>>>(ws, ws);
  kd3_bn1fin<<<1, 64, 0, stream>>>(ws, bn3g, bn3b);
  kd4_bn1apply<<<108416, 256, 0, stream>>>(ws);
  kd5_conv2<<<1024, 192, 0, stream>>>(ws, c2w, c2b, ws);
  kd6_bn2part<<<1024, 64, 0, stream>>>(ws, ws);
  kd7_bn2fin<<<1, 64, 0, stream>>>(ws, bn2g, bn2b);
  kd8_tokens<<<20736, 256, 0, stream>>>(ws);

  // transformer layers
  for (int l = 0; l < 2; ++l) {
    kd9_ln<<<324, 256, 0, stream>>>(ws, ws, OFF_X0, OFF_H, ln1g, ln1b, l);
    kd10_qkv<<<62208, 256, 0, stream>>>(ws, ws, wq, wk, wv, l);
    kd11_rot<<<20736, 256, 0, stream>>>(ws);
    kd12_attn<<<1296, 256, 0, stream>>>(ws, ws, gng, gnb, l);
    kd13_gate<<<20736, 256, 0, stream>>>(ws, ws, wg, l);
    kd14_wo<<<20736, 256, 0, stream>>>(ws, ws, wo, l);
    kd9_ln<<<324, 256, 0, stream>>>(ws, ws, OFF_Y, OFF_H, ln2g, ln2b, l);
    kd16_ffn1<<<41472, 256, 0, stream>>>(ws, ws, fw1, fb1, l);
    kd17_ffn2<<<20736, 256, 0, stream>>>(ws, ws, fw2, fb2, l);
  }

  kd18_cls<<<64, 256, 0, stream>>>(ws, nn1w, nn1b, out);
}

// Round 6
// 1705.135 us; speedup vs baseline: 3.4246x; 1.9351x over previous
//
#include <hip/hip_runtime.h>
#include <math.h>

#define EPS 1e-5f

// ---------------- float offsets in ws ----------------
#define OFF_A  0u          // conv1 out [1024][8][28][11][11] = 27,754,496 (dead after conv2)
#define OFF_X0 0u          // tokens x  [1024][81][64] = 5,308,416 (written after A dead)
#define OFF_Y  31850496u   // y         [1024][81][64]
#define OFF_B  47775744u   // conv2 out [1024][64][81] = 5,308,416
#define OFF_P  53084160u   // partials  131,072
#define OFF_ST 53215232u   // scale1[8] shift1[8] scale2[64] shift2[64]

__device__ inline float dot64_lds(const float* xrow, const float* Wst, int kk) {
  const float4* xr = (const float4*)xrow;
  float acc = 0.f;
#pragma unroll
  for (int d4 = 0; d4 < 16; ++d4) {
    float4 xv = xr[d4];
    acc = fmaf(xv.x, Wst[(d4*4+0)*16+kk], acc);
    acc = fmaf(xv.y, Wst[(d4*4+1)*16+kk], acc);
    acc = fmaf(xv.z, Wst[(d4*4+2)*16+kk], acc);
    acc = fmaf(xv.w, Wst[(d4*4+3)*16+kk], acc);
  }
  return acc;
}

// ---------------- kd1: conv3d + bias -> A ----------------
__global__ __launch_bounds__(256) void kd1_conv1(const float* X, const float* c3w,
                                                 const float* c3b, float* ws) {
  int idx = blockIdx.x * 256 + threadIdx.x;
  if (idx >= 27754496) return;
  int pos = idx;
  int w = pos % 11; pos /= 11;
  int h = pos % 11; pos /= 11;
  int dd = pos % 28; pos /= 28;
  int o1 = pos % 8;
  int b = pos / 8;
  const float* Xb = X + (size_t)b * 5070;
  float a = c3b[o1];
#pragma unroll
  for (int kd = 0; kd < 3; ++kd)
#pragma unroll
    for (int kh = 0; kh < 3; ++kh)
#pragma unroll
      for (int kw = 0; kw < 3; ++kw)
        a = fmaf(Xb[(dd+kd)*169 + (h+kh)*13 + (w+kw)],
                 c3w[o1*27 + kd*9 + kh*3 + kw], a);
  ws[OFF_A + idx] = a;
}

// ---------------- kd2: BN1 partial sums per (b, o1) ----------------
__global__ __launch_bounds__(256) void kd2_bn1part(const float* ws_in, float* ws) {
  __shared__ float sS[256], sQ[256];
  int blk = blockIdx.x;               // b*8 + o1
  int tid = threadIdx.x;
  const float* Ab = ws_in + OFF_A + (size_t)blk * 3388;
  float S = 0.f, Q = 0.f;
  for (int i = tid; i < 3388; i += 256) {
    float v = Ab[i];
    S += v; Q += v * v;
  }
  sS[tid] = S; sQ[tid] = Q;
  __syncthreads();
  for (int st = 128; st > 0; st >>= 1) {
    if (tid < st) { sS[tid] += sS[tid+st]; sQ[tid] += sQ[tid+st]; }
    __syncthreads();
  }
  if (tid == 0) {
    ws[OFF_P + blk*2]     = sS[0];
    ws[OFF_P + blk*2 + 1] = sQ[0];
  }
}

// ---------------- kd3: BN1 finalize ----------------
__global__ void kd3_bn1fin(float* ws, const float* bn3g, const float* bn3b) {
  int t = threadIdx.x;
  if (t < 8) {
    float S = 0.f, Q = 0.f;
    for (int j = t; j < 8192; j += 8) {
      S += ws[OFF_P + j*2];
      Q += ws[OFF_P + j*2 + 1];
    }
    float n = 3469312.f;
    float mean = S / n;
    float var = Q / n - mean * mean;
    float sc = bn3g[t] * rsqrtf(var + EPS);
    ws[OFF_ST + t]     = sc;
    ws[OFF_ST + 8 + t] = bn3b[t] - mean * sc;
  }
}

// ---------------- kd5: conv2, per-batch LDS-tiled; BN1+relu applied at staging ----------------
__global__ __launch_bounds__(192) void kd5_conv2(const float* ws_in, const float* c2w,
                                                 const float* c2b, float* ws) {
  __shared__ float wl[4752];    // [kk 9][ciL 8][oc pad 66]
  __shared__ float inl[1056];   // [ciL 8][11 rows x 12]
  __shared__ float bn1[16];
  int tid = threadIdx.x;
  int b = blockIdx.x;
  int o = tid / 3, q = tid - o*3;
  if (tid < 16) bn1[tid] = ws_in[OFF_ST + tid];
  const float* Ab = ws_in + OFF_A + (size_t)b * 27104;   // [224][11][11]
  float acc[3][9];
#pragma unroll
  for (int ir = 0; ir < 3; ++ir)
#pragma unroll
    for (int x = 0; x < 9; ++x) acc[ir][x] = 0.f;

  for (int cc = 0; cc < 28; ++cc) {
    __syncthreads();
#pragma unroll
    for (int it = 0; it < 24; ++it) {
      int j = tid + 192*it;
      int og = j / 72, r = j - og*72;
      int ciL = r / 9, kk = r - ciL*9;
      wl[kk*528 + ciL*66 + og] = c2w[(og*224 + cc*8 + ciL)*9 + kk];
    }
#pragma unroll
    for (int it = 0; it < 6; ++it) {
      int e = tid + 192*it;
      if (e < 968) {
        int ciL = e / 121, pos = e - ciL*121;
        int h = pos / 11, w = pos - h*11;
        int ci = cc*8 + ciL;
        int o1 = ci / 28;
        float raw = Ab[(size_t)ci*121 + pos];
        float v = bn1[o1]*raw + bn1[8+o1];
        inl[ciL*132 + h*12 + w] = fmaxf(v, 0.f);
      }
    }
    __syncthreads();
    for (int ciL = 0; ciL < 8; ++ciL) {
      float rr[5][12];
#pragma unroll
      for (int r5 = 0; r5 < 5; ++r5) {
        const float4* rp = (const float4*)(inl + ciL*132 + (q*3 + r5)*12);
        float4 A4 = rp[0], B4 = rp[1], C4 = rp[2];
        rr[r5][0]=A4.x; rr[r5][1]=A4.y; rr[r5][2]=A4.z; rr[r5][3]=A4.w;
        rr[r5][4]=B4.x; rr[r5][5]=B4.y; rr[r5][6]=B4.z; rr[r5][7]=B4.w;
        rr[r5][8]=C4.x; rr[r5][9]=C4.y; rr[r5][10]=C4.z; rr[r5][11]=C4.w;
      }
#pragma unroll
      for (int ki = 0; ki < 3; ++ki) {
#pragma unroll
        for (int kj = 0; kj < 3; ++kj) {
          float wv = wl[(ki*3+kj)*528 + ciL*66 + o];
#pragma unroll
          for (int ir = 0; ir < 3; ++ir)
#pragma unroll
            for (int x = 0; x < 9; ++x)
              acc[ir][x] = fmaf(rr[ir+ki][x+kj], wv, acc[ir][x]);
        }
      }
    }
  }
  float bias = c2b[o];
  float* b2 = ws + OFF_B + ((size_t)b*64 + o)*81;
#pragma unroll
  for (int ir = 0; ir < 3; ++ir)
#pragma unroll
    for (int x = 0; x < 9; ++x)
      b2[(q*3+ir)*9 + x] = acc[ir][x] + bias;
}

// ---------------- kd6: BN2 partials per b ----------------
__global__ void kd6_bn2part(const float* ws_in, float* ws) {
  int b = blockIdx.x, t = threadIdx.x;  // t = channel
  const float* Bb = ws_in + OFF_B + (size_t)b * 5184 + t * 81;
  float S = 0.f, Q = 0.f;
  for (int s = 0; s < 81; ++s) {
    float v = Bb[s];
    S += v; Q += v * v;
  }
  ws[OFF_P + b*128 + t]      = S;
  ws[OFF_P + b*128 + 64 + t] = Q;
}

// ---------------- kd7: BN2 finalize ----------------
__global__ void kd7_bn2fin(float* ws, const float* bn2g, const float* bn2b) {
  int t = threadIdx.x;
  float S = 0.f, Q = 0.f;
  for (int b = 0; b < 1024; ++b) {
    S += ws[OFF_P + b*128 + t];
    Q += ws[OFF_P + b*128 + 64 + t];
  }
  float n = 82944.f;
  float mean = S / n;
  float var = Q / n - mean * mean;
  float sc = bn2g[t] * rsqrtf(var + EPS);
  ws[OFF_ST + 16 + t] = sc;
  ws[OFF_ST + 80 + t] = bn2b[t] - mean * sc;
}

// ---------------- kd8: BN2 apply + relu + transpose -> X0 [b][s][64] ----------------
__global__ __launch_bounds__(256) void kd8_tokens(float* ws) {
  int idx = blockIdx.x * 256 + threadIdx.x;
  if (idx >= 5308416) return;
  int o = idx % 64;
  int s = (idx / 64) % 81;
  int b = idx / 5184;
  float v = ws[OFF_ST + 16 + o] * ws[OFF_B + (size_t)b*5184 + o*81 + s] + ws[OFF_ST + 80 + o];
  ws[OFF_X0 + idx] = fmaxf(v, 0.f);
}

// ---------------- fa_layer: LN1 + QKV + rotary + retention + groupnorm + gate + wo + residual ----------------
__global__ __launch_bounds__(256) void fa_layer(const float* ws_in, float* ws,
    const float* wq, const float* wk, const float* wv, const float* wgp, const float* wop,
    const float* ln1g, const float* ln1b, const float* gng, const float* gnb, int l)
{
  __shared__ __align__(16) float H[5184];
  __shared__ __align__(16) float Yb[5184];   // x-scratch -> Yc -> Z
  __shared__ float qb[1296];
  __shared__ float kb[1296];
  __shared__ float vb[1296];
  __shared__ float Wst[1024];
  __shared__ float muv[81], rsd[81];
  const int tid = threadIdx.x;
  const int b = blockIdx.x;
  const float* xg = ws_in + OFF_X0 + (size_t)b * 5184;

  // 1. load x -> Yb (coalesced)
  for (int u = tid; u < 5184; u += 256) Yb[u] = xg[u];
  __syncthreads();
  // 2. LN1 stats (exact kd9 order)
  if (tid < 81) {
    const float* xr = Yb + tid*64;
    float sv = 0.f;
    for (int d = 0; d < 64; ++d) sv += xr[d];
    float mean = sv * (1.f/64.f);
    float sq = 0.f;
    for (int d = 0; d < 64; ++d) { float dv = xr[d]-mean; sq += dv*dv; }
    muv[tid] = mean;
    rsd[tid] = rsqrtf(sq*(1.f/64.f) + EPS);
  }
  __syncthreads();
  // 3. H = LN1(x)
  for (int u = tid; u < 5184; u += 256) {
    int s = u >> 6, d = u & 63;
    H[u] = (Yb[u] - muv[s])*rsd[s]*ln1g[l*64+d] + ln1b[l*64+d];
  }
  // Yb (x copy) dead from here; x re-read from global for residual.

  // 4. heads
  for (int hd = 0; hd < 4; ++hd) {
    for (int m = 0; m < 3; ++m) {
      __syncthreads();
      const float* src = (m==0) ? wq : (m==1) ? wk : wv;
      const float* wbase = src + (size_t)(l*4 + hd) * 1024;   // [d][16]
      for (int u = tid; u < 1024; u += 256) Wst[u] = wbase[u];
      __syncthreads();
      float* dst = (m==0) ? qb : (m==1) ? kb : vb;
      for (int u = tid; u < 1296; u += 256) {
        int s = u >> 4, kk = u & 15;
        dst[u] = dot64_lds(H + s*64, Wst, kk);
      }
    }
    __syncthreads();
    // rotary (kd11 clone): m=0 -> qb (cu=c*xs), m=1 -> kb (cu=c/xs)
    for (int u = tid; u < 1296; u += 256) {
      int m = u / 648;
      int r = u - m*648;
      int p = r & 7, s = r >> 3;
      float scale = (2.f*p + 6.4f) / 22.4f;
      float xs = powf(scale, (float)s / 512.f);
      float invf = powf(10000.f, -(float)p / 8.f);
      float ang = (float)s * invf;
      float c = cosf(ang), sn = sinf(ang);
      float cu, su;
      if (m == 0) { cu = c*xs; su = sn*xs; }
      else        { cu = c/xs; su = sn/xs; }
      float* ptr = (m == 0 ? qb : kb) + s*16 + 2*p;
      float a = ptr[0], bb2 = ptr[1];
      ptr[0] = a*cu - bb2*su;
      ptr[1] = bb2*cu + a*su;
    }
    __syncthreads();
    // retention attention + groupnorm (kd12 clone), row-serial
    if (tid < 81) {
      int s = tid;
      float g = 1.f - expf(-3.4657359f + (float)hd * (-0.92419624f));
      float lg = log2f(g);
      float q[16];
#pragma unroll
      for (int k = 0; k < 16; ++k) q[k] = qb[s*16+k];
      float yh[16];
#pragma unroll
      for (int v = 0; v < 16; ++v) yh[v] = 0.f;
      for (int tt = 0; tt <= s; ++tt) {
        const float* Kr = kb + tt*16;
        float a = 0.f;
#pragma unroll
        for (int k = 0; k < 16; ++k) a = fmaf(q[k], Kr[k], a);
        a *= exp2f((float)(s - tt) * lg);
        const float* Vr = vb + tt*16;
#pragma unroll
        for (int v = 0; v < 16; ++v) yh[v] = fmaf(a, Vr[v], yh[v]);
      }
      float sv = 0.f;
#pragma unroll
      for (int v = 0; v < 16; ++v) sv += yh[v];
      float mean = sv * (1.f/16.f);
      float sq = 0.f;
#pragma unroll
      for (int v = 0; v < 16; ++v) { float dv = yh[v]-mean; sq += dv*dv; }
      float rstd = rsqrtf(sq*(1.f/16.f) + EPS);
#pragma unroll
      for (int v = 0; v < 16; ++v) {
        int col = hd*16 + v;
        Yb[s*64 + col] = (yh[v]-mean)*rstd*gng[l*64+col] + gnb[l*64+col];
      }
    }
  }

  // 5. gate: Z = silu(G) * Yc in place (G = H @ wg)
  for (int cc = 0; cc < 4; ++cc) {
    __syncthreads();
    for (int u = tid; u < 1024; u += 256) {
      int d = u >> 4, c = u & 15;
      Wst[u] = wgp[(l*64+d)*64 + cc*16 + c];
    }
    __syncthreads();
    for (int u = tid; u < 1296; u += 256) {
      int s = u >> 4, c = u & 15;
      float G = dot64_lds(H + s*64, Wst, c);
      float sig = 1.f / (1.f + expf(-G));
      Yb[s*64 + cc*16 + c] *= G*sig;
    }
  }

  // 6. wo: y = Z @ wo + x  -> global OFF_Y
  float* yg = ws + OFF_Y + (size_t)b * 5184;
  for (int cc = 0; cc < 4; ++cc) {
    __syncthreads();
    for (int u = tid; u < 1024; u += 256) {
      int d = u >> 4, c = u & 15;
      Wst[u] = wop[(l*64+d)*64 + cc*16 + c];
    }
    __syncthreads();
    for (int u = tid; u < 1296; u += 256) {
      int s = u >> 4, c = u & 15;
      float a = dot64_lds(Yb + s*64, Wst, c);
      yg[s*64 + cc*16 + c] = a + xg[s*64 + cc*16 + c];
    }
  }
}

// ---------------- ff_layer: LN2 + FFN (4 f-quarters) + residual -> x' ----------------
__global__ __launch_bounds__(256) void ff_layer(const float* ws_in, float* ws,
    const float* fw1, const float* fb1, const float* fw2, const float* fb2,
    const float* ln2g, const float* ln2b, int l)
{
  __shared__ __align__(16) float H2[5184];
  __shared__ float F1q[2592];   // [81][32]
  __shared__ float Wst[1024];
  __shared__ float muv[81], rsd[81];
  const int tid = threadIdx.x;
  const int b = blockIdx.x;
  const float* yg = ws_in + OFF_Y + (size_t)b * 5184;

  for (int u = tid; u < 5184; u += 256) H2[u] = yg[u];
  __syncthreads();
  if (tid < 81) {
    const float* xr = H2 + tid*64;
    float sv = 0.f;
    for (int d = 0; d < 64; ++d) sv += xr[d];
    float mean = sv * (1.f/64.f);
    float sq = 0.f;
    for (int d = 0; d < 64; ++d) { float dv = xr[d]-mean; sq += dv*dv; }
    muv[tid] = mean;
    rsd[tid] = rsqrtf(sq*(1.f/64.f) + EPS);
  }
  __syncthreads();
  for (int u = tid; u < 5184; u += 256) {
    int s = u >> 6, d = u & 63;
    H2[u] = (H2[u] - muv[s])*rsd[s]*ln2g[l*64+d] + ln2b[l*64+d];
  }

  float acc[21];
#pragma unroll
  for (int i = 0; i < 21; ++i) acc[i] = 0.f;

  for (int qq = 0; qq < 4; ++qq) {
    // ffn1 quarter -> F1q
    for (int cc = 0; cc < 2; ++cc) {
      __syncthreads();
      int f0 = qq*32 + cc*16;
      for (int u = tid; u < 1024; u += 256) {
        int d = u >> 4, c = u & 15;
        Wst[u] = fw1[(l*64+d)*128 + f0 + c];
      }
      __syncthreads();
      for (int u = tid; u < 1296; u += 256) {
        int s = u >> 4, c = u & 15;
        float p = dot64_lds(H2 + s*64, Wst, c) + fb1[l*128 + f0 + c];
        F1q[s*32 + cc*16 + c] = 0.5f*p*(1.f + erff(p*0.70710678118f));
      }
    }
    // ffn2 quarter accumulate
    for (int fc = 0; fc < 2; ++fc) {
      __syncthreads();
      int fbase = qq*32 + fc*16;
      for (int u = tid; u < 1024; u += 256) {
        int f = u >> 6, c = u & 63;
        Wst[u] = fw2[(l*128 + fbase + f)*64 + c];
      }
      __syncthreads();
#pragma unroll
      for (int i = 0; i < 21; ++i) {
        int u = tid + 256*i;
        if (u < 5184) {
          int s = u >> 6, c = u & 63;
          const float* fr = F1q + s*32 + fc*16;
          float a = 0.f;
#pragma unroll
          for (int f = 0; f < 16; ++f) a = fmaf(fr[f], Wst[f*64 + c], a);
          acc[i] += a;
        }
      }
    }
  }
  // x' = acc + fb2 + y
  float* xg = ws + OFF_X0 + (size_t)b * 5184;
#pragma unroll
  for (int i = 0; i < 21; ++i) {
    int u = tid + 256*i;
    if (u < 5184) {
      int c = u & 63;
      xg[u] = acc[i] + fb2[l*64 + c] + yg[u];
    }
  }
}

// ---------------- fcls: classifier, one block per batch ----------------
__global__ __launch_bounds__(256) void fcls(const float* ws_in, const float* nn1w,
                                            const float* nn1b, float* out) {
  __shared__ float red[256];
  const int tid = threadIdx.x;
  const int b = blockIdx.x;
  const float* Xr = ws_in + OFF_X0 + (size_t)b * 5184;
  int c = tid & 15, chunk = tid >> 4;
  int i0 = chunk * 324;
  float a = 0.f;
  for (int i = 0; i < 324; ++i)
    a = fmaf(Xr[i0+i], nn1w[(size_t)(i0+i)*16 + c], a);
  red[tid] = a;
  __syncthreads();
  if (tid < 16) {
    float s = nn1b[tid];
#pragma unroll
    for (int j = 0; j < 16; ++j) s += red[j*16 + tid];
    out[b*16 + tid] = s;
  }
}

// ---------------- launch ----------------
extern "C" void kernel_launch(void* const* d_in, const int* in_sizes, int n_in,
                              void* d_out, int out_size, void* d_ws, size_t ws_size,
                              hipStream_t stream) {
  const float* X    = (const float*)d_in[0];
  const float* c3w  = (const float*)d_in[1];
  const float* c3b  = (const float*)d_in[2];
  const float* bn3g = (const float*)d_in[3];
  const float* bn3b = (const float*)d_in[4];
  const float* c2w  = (const float*)d_in[5];
  const float* c2b  = (const float*)d_in[6];
  const float* bn2g = (const float*)d_in[7];
  const float* bn2b = (const float*)d_in[8];
  const float* wq   = (const float*)d_in[9];
  const float* wk   = (const float*)d_in[10];
  const float* wv   = (const float*)d_in[11];
  const float* wg   = (const float*)d_in[12];
  const float* wo   = (const float*)d_in[13];
  const float* gng  = (const float*)d_in[14];
  const float* gnb  = (const float*)d_in[15];
  const float* ln1g = (const float*)d_in[16];
  const float* ln1b = (const float*)d_in[17];
  const float* ln2g = (const float*)d_in[18];
  const float* ln2b = (const float*)d_in[19];
  const float* fw1  = (const float*)d_in[20];
  const float* fb1  = (const float*)d_in[21];
  const float* fw2  = (const float*)d_in[22];
  const float* fb2  = (const float*)d_in[23];
  const float* nn1w = (const float*)d_in[24];
  const float* nn1b = (const float*)d_in[25];
  float* ws = (float*)d_ws;
  float* out = (float*)d_out;

  // conv stage
  kd1_conv1<<<108416, 256, 0, stream>>>(X, c3w, c3b, ws);
  kd2_bn1part<<<8192, 256, 0, stream>>>(ws, ws);
  kd3_bn1fin<<<1, 64, 0, stream>>>(ws, bn3g, bn3b);
  kd5_conv2<<<1024, 192, 0, stream>>>(ws, c2w, c2b, ws);   // BN1+relu fused into staging
  kd6_bn2part<<<1024, 64, 0, stream>>>(ws, ws);
  kd7_bn2fin<<<1, 64, 0, stream>>>(ws, bn2g, bn2b);
  kd8_tokens<<<20736, 256, 0, stream>>>(ws);

  // transformer layers (fused per-batch)
  for (int l = 0; l < 2; ++l) {
    fa_layer<<<1024, 256, 0, stream>>>(ws, ws, wq, wk, wv, wg, wo,
                                       ln1g, ln1b, gng, gnb, l);
    ff_layer<<<1024, 256, 0, stream>>>(ws, ws, fw1, fb1, fw2, fb2,
                                       ln2g, ln2b, l);
  }

  fcls<<<1024, 256, 0, stream>>>(ws, nn1w, nn1b, out);
}